// Round 9
// baseline (114.372 us; speedup 1.0000x reference)
//
#include <hip/hip_runtime.h>
#include <hip/hip_bf16.h>
#include <math.h>

typedef short bf16x8 __attribute__((ext_vector_type(8)));
typedef float f32x4 __attribute__((ext_vector_type(4)));

#define STATE 24
#define L1N 100

// ---- bf16 weight image in d_ws (u32 units), biases folded in ----
// W1: 100 rows x 20 u32 (40 halves), col24 = b1
// W2: 100 rows x 68 u32 (136 halves), col100 = b2
// Wh: 27 rows x 68 u32, col100 = head bias
#define IMG_U32 10752
#define W1_STRIDE 40
#define K_STRIDE 136
#define W2_HOFF 4000
#define WH_HOFF 17600

// ---- per-wave LDS: two 16-row X buffers + 32-row f32 stage ----
#define X_HALVES (16 * K_STRIDE)        // 2176
#define STAGE_DW 46                      // dword stride (<=2-way banks)
#define WAVE_HALVES (2 * X_HALVES + 32 * STAGE_DW * 2)   // 7296
#define GRID 512                         // 2 blocks/CU (VGPR-bound)

__device__ __constant__ int CHOFF[21] = {0,6,7,12,13,14,18,19,20,21,24,25,26,27,28,30,31,32,33,34,35};
__device__ __constant__ int ZOFF[15]  = {1,2,3,4,5,8,9,10,11,15,16,17,22,23,29};

__device__ inline unsigned pkbf(float lo, float hi) {
    __hip_bfloat162 h = __float22bfloat162_rn(float2{lo, hi});
    return *(const unsigned*)&h;
}
__device__ inline float fast_tanh(float x) {
    float e = __builtin_amdgcn_exp2f(x * 2.8853900817779268f);
    return 1.0f - 2.0f * __builtin_amdgcn_rcpf(e + 1.0f);
}
__device__ inline float fast_softplus(float v) {
    float u = __builtin_amdgcn_exp2f(fabsf(v) * -1.4426950408889634f);
    float l = __builtin_amdgcn_logf(1.0f + u) * 0.6931471805599453f;
    return fmaxf(v, 0.0f) + l;
}

__global__ __launch_bounds__(256) void prep_weights(
    const float* __restrict__ W1, const float* __restrict__ b1,
    const float* __restrict__ W2, const float* __restrict__ b2,
    const float* __restrict__ Wm, const float* __restrict__ bm,
    const float* __restrict__ Wc, const float* __restrict__ bc,
    unsigned* __restrict__ img)
{
    int i = blockIdx.x * 256 + threadIdx.x;
    if (i >= IMG_U32) return;
    float lo = 0.f, hi = 0.f;
    if (i < 2000) {
        int r = i / 20, k = (i % 20) * 2;
        if (k < STATE)      { lo = W1[r * STATE + k]; hi = W1[r * STATE + k + 1]; }
        else if (k == STATE)  lo = b1[r];
    } else if (i < 8800) {
        int j = i - 2000, r = j / 68, k = (j % 68) * 2;
        if (k < L1N)      { lo = W2[r * L1N + k]; hi = (k + 1 < L1N) ? W2[r * L1N + k + 1] : 0.f; }
        else if (k == L1N)  lo = b2[r];
    } else if (i < 10636) {
        int j = i - 8800, r = j / 68, k = (j % 68) * 2;
        const float* src; float bias;
        if (r < 6) { src = Wm + r * L1N; bias = bm[r]; }
        else       { src = Wc + (r - 6) * L1N; bias = bc[r - 6]; }
        if (k < L1N)      { lo = src[k]; hi = (k + 1 < L1N) ? src[k + 1] : 0.f; }
        else if (k == L1N)  lo = bias;
    }
    img[i] = pkbf(lo, hi);
}

// A = weights (M = features, register-resident), B = activations (N = rows).
// D lane map: col=lane&15 = batch row, row=q*4+i = feature.
// Two 16-row pipelines (u0 -> Xa, u1 -> Xb) interleaved to self-hide
// ds_write -> ds_read latency within one wave.
__global__ __launch_bounds__(256, 2) void actor_mfma(
    const float* __restrict__ states,
    const unsigned* __restrict__ img,
    float* __restrict__ out_mean, float* __restrict__ out_chol, int ntiles)
{
    __shared__ __align__(16) unsigned short smem[4 * WAVE_HALVES];   // 58368 B
    const int tid = threadIdx.x;
    const int wave = tid >> 6, lane = tid & 63, q = lane >> 4, c = lane & 15;
    unsigned short* base = smem + wave * WAVE_HALVES;
    unsigned short* Xbuf[2] = { base, base + X_HALVES };
    float* stage = (float*)(base + 2 * X_HALVES);   // 32 rows x STAGE_DW f32

    // ---- weights into registers (img is L2/L3-hot) ----
    const unsigned short* imgh = (const unsigned short*)img;
    bf16x8 wf1[7], wf2[4][7], wf3[4][2];
    #pragma unroll
    for (int nt = 0; nt < 7; ++nt) {
        int wr = nt * 16 + c; wr = wr < L1N ? wr : L1N - 1;
        wf1[nt] = *(const bf16x8*)(imgh + wr * W1_STRIDE + q * 8);
        #pragma unroll
        for (int ks = 0; ks < 4; ++ks)
            wf2[ks][nt] = *(const bf16x8*)(imgh + W2_HOFF + wr * K_STRIDE + ks * 32 + q * 8);
    }
    #pragma unroll
    for (int ht = 0; ht < 2; ++ht) {
        int wr = ht * 16 + c; wr = wr < 27 ? wr : 26;
        #pragma unroll
        for (int ks = 0; ks < 4; ++ks)
            wf3[ks][ht] = *(const bf16x8*)(imgh + WH_HOFF + wr * K_STRIDE + ks * 32 + q * 8);
    }

    // ---- one-time LDS init: X pad cols (bias lane) + stage tril zeros ----
    {
        unsigned* xa = (unsigned*)Xbuf[0];
        unsigned* xb = (unsigned*)Xbuf[1];
        #pragma unroll
        for (int it = 0; it < 4; ++it) {        // 16 rows x u32 cols 50..63
            int idx = it * 64 + lane;
            if (idx < 224) {
                int r = idx / 14, s = idx - r * 14;
                unsigned v = (s == 0) ? 0x00003F80u : 0u;   // col100 = bf16(1.0)
                xa[r * 68 + 50 + s] = v;
                xb[r * 68 + 50 + s] = v;
            }
        }
        #pragma unroll
        for (int it = 0; it < 8; ++it) {        // 32 rows x 15 tril zeros, ONCE
            int idx = it * 64 + lane;
            if (idx < 480) {
                int r = idx / 15;
                stage[r * STAGE_DW + ZOFF[idx - r * 15]] = 0.f;
            }
        }
    }

    // per-lane epilogue routing
    int scol[8], skind[8];
    #pragma unroll
    for (int ht = 0; ht < 2; ++ht)
        #pragma unroll
        for (int i = 0; i < 4; ++i) {
            int f = ht * 16 + q * 4 + i, e = ht * 4 + i;
            if (f < 6)       { scol[e] = 36 + f;        skind[e] = 0; }
            else if (f < 27) { scol[e] = CHOFF[f - 6];  skind[e] = 1; }
            else             { scol[e] = 0;             skind[e] = -1; }
        }

    float4 sv[4];
    auto loadStates = [&](int tt) {
        if (tt < ntiles && q < 3) {
            #pragma unroll
            for (int u = 0; u < 2; ++u) {
                const float* p = states + ((long)tt * 128 + wave * 32 + u * 16 + c) * STATE + q * 8;
                sv[u * 2]     = *(const float4*)p;
                sv[u * 2 + 1] = *(const float4*)(p + 4);
            }
        }
    };
    loadStates(blockIdx.x);

    for (int t = blockIdx.x; t < ntiles; t += GRID) {
        const long rowW = (long)t * 128 + wave * 32;

        union { bf16x8 v; unsigned u[4]; } sb[2];
        #pragma unroll
        for (int u = 0; u < 2; ++u) {
            if (q < 3) {
                sb[u].u[0] = pkbf(sv[u*2].x,   sv[u*2].y);
                sb[u].u[1] = pkbf(sv[u*2].z,   sv[u*2].w);
                sb[u].u[2] = pkbf(sv[u*2+1].x, sv[u*2+1].y);
                sb[u].u[3] = pkbf(sv[u*2+1].z, sv[u*2+1].w);
            } else {                  // k=24 carries 1.0 -> bias
                sb[u].u[0] = 0x00003F80u; sb[u].u[1] = sb[u].u[2] = sb[u].u[3] = 0u;
            }
        }
        loadStates(t + GRID);

        // ---- GEMM1 u0, u1 (writes drain while sibling computes) ----
        #pragma unroll
        for (int u = 0; u < 2; ++u) {
            unsigned short* X = Xbuf[u];
            #pragma unroll
            for (int nt = 0; nt < 7; ++nt) {
                f32x4 acc = {0.f, 0.f, 0.f, 0.f};
                acc = __builtin_amdgcn_mfma_f32_16x16x32_bf16(wf1[nt], sb[u].v, acc, 0, 0, 0);
                if (nt * 16 + q * 4 < L1N) {
                    uint2 pk = make_uint2(pkbf(fmaxf(acc[0], 0.f), fmaxf(acc[1], 0.f)),
                                          pkbf(fmaxf(acc[2], 0.f), fmaxf(acc[3], 0.f)));
                    *(uint2*)&X[c * K_STRIDE + nt * 16 + q * 4] = pk;
                }
            }
        }

        // ---- GEMM2 u0, u1 ----
        #pragma unroll
        for (int u = 0; u < 2; ++u) {
            unsigned short* X = Xbuf[u];
            bf16x8 ab[4];
            #pragma unroll
            for (int ks = 0; ks < 4; ++ks)
                ab[ks] = *(const bf16x8*)&X[c * K_STRIDE + ks * 32 + q * 8];
            #pragma unroll
            for (int nt = 0; nt < 7; ++nt) {
                f32x4 acc = {0.f, 0.f, 0.f, 0.f};
                #pragma unroll
                for (int ks = 0; ks < 4; ++ks)
                    acc = __builtin_amdgcn_mfma_f32_16x16x32_bf16(wf2[ks][nt], ab[ks], acc, 0, 0, 0);
                if (nt * 16 + q * 4 < L1N) {
                    uint2 pk = make_uint2(pkbf(fmaxf(acc[0], 0.f), fmaxf(acc[1], 0.f)),
                                          pkbf(fmaxf(acc[2], 0.f), fmaxf(acc[3], 0.f)));
                    *(uint2*)&X[c * K_STRIDE + nt * 16 + q * 4] = pk;
                }
            }
        }

        // ---- GEMM3 + epilogue per u ----
        #pragma unroll
        for (int u = 0; u < 2; ++u) {
            unsigned short* X = Xbuf[u];
            bf16x8 ab3[4];
            #pragma unroll
            for (int ks = 0; ks < 4; ++ks)
                ab3[ks] = *(const bf16x8*)&X[c * K_STRIDE + ks * 32 + q * 8];
            f32x4 acc3[2];
            acc3[0] = (f32x4){0.f, 0.f, 0.f, 0.f};
            acc3[1] = (f32x4){0.f, 0.f, 0.f, 0.f};
            #pragma unroll
            for (int ks = 0; ks < 4; ++ks)
                #pragma unroll
                for (int ht = 0; ht < 2; ++ht)
                    acc3[ht] = __builtin_amdgcn_mfma_f32_16x16x32_bf16(wf3[ks][ht], ab3[ks], acc3[ht], 0, 0, 0);
            float* srow = stage + (u * 16 + c) * STAGE_DW;
            #pragma unroll
            for (int e = 0; e < 8; ++e) {
                float v = acc3[e >> 2][e & 3];
                if (skind[e] == 0)      srow[scol[e]] = fast_tanh(v);
                else if (skind[e] == 1) srow[scol[e]] = fast_softplus(v);
            }
        }

        // ---- coalesced stores (same-wave DS ordering covers RAW) ----
        #pragma unroll
        for (int it = 0; it < 2; ++it) {   // mean: 32 rows x 6 f32 = 96 float2
            int j = it * 64 + lane;
            if (j < 96) {
                float2 m = *(const float2*)&stage[(j / 3) * STAGE_DW + 36 + (j % 3) * 2];
                *(float2*)(out_mean + rowW * 6 + j * 2) = m;
            }
        }
        #pragma unroll
        for (int it = 0; it < 5; ++it) {   // chol: 32 rows x 36 f32 = 288 float4
            int j = it * 64 + lane;
            if (j < 288) {
                float4 v = *(const float4*)&stage[(j / 9) * STAGE_DW + (j % 9) * 4];
                *(float4*)(out_chol + rowW * 36 + j * 4) = v;
            }
        }
    }
}

extern "C" void kernel_launch(void* const* d_in, const int* in_sizes, int n_in,
                              void* d_out, int out_size, void* d_ws, size_t ws_size,
                              hipStream_t stream) {
    const float* states = (const float*)d_in[0];
    const float* W1 = (const float*)d_in[1];
    const float* b1 = (const float*)d_in[2];
    const float* W2 = (const float*)d_in[3];
    const float* b2 = (const float*)d_in[4];
    const float* Wm = (const float*)d_in[5];
    const float* bm = (const float*)d_in[6];
    const float* Wc = (const float*)d_in[7];
    const float* bc = (const float*)d_in[8];

    const int batch = in_sizes[0] / STATE;                  // 262144
    float* out_mean = (float*)d_out;                        // [B,6]
    float* out_chol = out_mean + (size_t)batch * 6;         // [B,6,6]
    unsigned* img = (unsigned*)d_ws;

    prep_weights<<<(IMG_U32 + 255) / 256, 256, 0, stream>>>(W1, b1, W2, b2,
                                                            Wm, bm, Wc, bc, img);
    const int ntiles = batch / 128;                         // 2048 (128 rows/tile)
    actor_mfma<<<GRID, 256, 0, stream>>>(states, img, out_mean, out_chol, ntiles);
}